// Round 1
// baseline (2444.465 us; speedup 1.0000x reference)
//
#include <hip/hip_runtime.h>
#include <hip/hip_fp16.h>

typedef _Float16 half2_t __attribute__((ext_vector_type(2)));
typedef _Float16 half4_t __attribute__((ext_vector_type(4)));
typedef _Float16 half8_t __attribute__((ext_vector_type(8)));
typedef float floatx4 __attribute__((ext_vector_type(4)));

#define B_   32
#define S_   512
#define D_   768
#define H_   384
#define H3_  1152      // 3*H
#define M_   (B_*S_)   // 16384
#define N2_  (2*H3_)   // 2304
#define TWOH_ 768
#define NWG_DIR 6
#define JSPAN 64       // j-slice per WG

// ---- coherent (system-scope) batched 16B loads: 6 chunks, one vmcnt ----
__device__ __forceinline__ void load16_cc6(unsigned long long a0, unsigned long long a1,
                                           unsigned long long a2, unsigned long long a3,
                                           unsigned long long a4, unsigned long long a5,
                                           int4& v0, int4& v1, int4& v2,
                                           int4& v3, int4& v4, int4& v5) {
  asm volatile("global_load_dwordx4 %0, %6, off sc0 sc1\n\t"
               "global_load_dwordx4 %1, %7, off sc0 sc1\n\t"
               "global_load_dwordx4 %2, %8, off sc0 sc1\n\t"
               "global_load_dwordx4 %3, %9, off sc0 sc1\n\t"
               "global_load_dwordx4 %4, %10, off sc0 sc1\n\t"
               "global_load_dwordx4 %5, %11, off sc0 sc1\n\t"
               "s_waitcnt vmcnt(0)"
               : "=&v"(v0), "=&v"(v1), "=&v"(v2), "=&v"(v3), "=&v"(v4), "=&v"(v5)
               : "v"(a0), "v"(a1), "v"(a2), "v"(a3), "v"(a4), "v"(a5)
               : "memory");
}
__device__ __forceinline__ void store4_cc(unsigned long long a, unsigned d) {
  asm volatile("global_store_dword %0, %1, off sc0 sc1" :: "v"(a), "v"(d) : "memory");
}

// ---------------- generic fp32 -> fp16 convert (vec4) ----------------
__global__ void cvt_f32_f16_kernel(const float* __restrict__ src,
                                   _Float16* __restrict__ dst, int n4) {
  int i = blockIdx.x * blockDim.x + threadIdx.x;
  if (i >= n4) return;
  float4 v = ((const float4*)src)[i];
  half4_t h = {(_Float16)v.x, (_Float16)v.y, (_Float16)v.z, (_Float16)v.w};
  ((half4_t*)dst)[i] = h;
}

// ---------------- input-projection GEMM (fp16 MFMA) ----------------
__global__ __launch_bounds__(256) void gemm_xw_kernel(
    const _Float16* __restrict__ A, const _Float16* __restrict__ Bm,
    const float* __restrict__ bias_f, const float* __restrict__ bias_b,
    _Float16* __restrict__ xw) {
  __shared__ _Float16 As[64][40];
  __shared__ _Float16 Bs[64][40];
  const int m0 = blockIdx.x * 64, n0 = blockIdx.y * 64;
  const int tid = threadIdx.x, lane = tid & 63, w = tid >> 6;
  const int wm = w >> 1, wn = w & 1;
  const int q = lane >> 4, c = lane & 15;
  floatx4 acc[2][2] = {};

  const int t = tid & 127;
  const int srow = t >> 1, skh = (t & 1) * 16;
  const _Float16* gsrc =
      (tid < 128 ? A + (size_t)(m0 + srow) * D_ : Bm + (size_t)(n0 + srow) * D_) + skh;
  _Float16* ldst = (tid < 128) ? &As[srow][skh] : &Bs[srow][skh];

  for (int k0 = 0; k0 < D_; k0 += 32) {
    half8_t v0 = *(const half8_t*)(gsrc + k0);
    half8_t v1 = *(const half8_t*)(gsrc + k0 + 8);
    __syncthreads();
    *(half8_t*)ldst = v0;
    *(half8_t*)(ldst + 8) = v1;
    __syncthreads();
    half8_t a0 = *(const half8_t*)&As[wm * 32 + c][q * 8];
    half8_t a1 = *(const half8_t*)&As[wm * 32 + 16 + c][q * 8];
    half8_t b0 = *(const half8_t*)&Bs[wn * 32 + c][q * 8];
    half8_t b1 = *(const half8_t*)&Bs[wn * 32 + 16 + c][q * 8];
    acc[0][0] = __builtin_amdgcn_mfma_f32_16x16x32_f16(a0, b0, acc[0][0], 0, 0, 0);
    acc[0][1] = __builtin_amdgcn_mfma_f32_16x16x32_f16(a0, b1, acc[0][1], 0, 0, 0);
    acc[1][0] = __builtin_amdgcn_mfma_f32_16x16x32_f16(a1, b0, acc[1][0], 0, 0, 0);
    acc[1][1] = __builtin_amdgcn_mfma_f32_16x16x32_f16(a1, b1, acc[1][1], 0, 0, 0);
  }
  for (int mi = 0; mi < 2; ++mi)
    for (int ni = 0; ni < 2; ++ni)
      for (int r = 0; r < 4; ++r) {
        int m = m0 + wm * 32 + mi * 16 + q * 4 + r;
        int n = n0 + wn * 32 + ni * 16 + c;
        int dir = n >= H3_;
        int nn = n - dir * H3_;
        float bv = dir ? bias_b[nn] : bias_f[nn];
        float vv = acc[mi][ni][r] + bv;
        int s = m & (S_ - 1), bb = m >> 9;
        xw[(((size_t)dir * S_ + s) * B_ + bb) * H3_ + nn] = (_Float16)vv;
      }
}

// ---------------- GRU recurrence v4: tag-in-data handshake ----------------
// 12 WGs = 2 dirs x 6 slices of 64 j. 512 threads = 8 waves = 2 btiles x 4 jtiles.
// h exchanged as tagged dwords {step_tag<<16 | half}: the gather IS the poll
// (no flag, no producer drain). Parity double-buffered hT keeps <=1-step skew
// safe. Gate math runs in MFMA C-layout registers (no ghS LDS roundtrip);
// hS is parity double-buffered -> ONE __syncthreads per step.
__global__ __launch_bounds__(512, 2) void gru_mfma_kernel(
    const _Float16* __restrict__ xw,    // [2][512][32][1152]
    const _Float16* __restrict__ Whh,   // [2][1152][384] fp16 row-major
    const float* __restrict__ bhh_f, const float* __restrict__ bhh_b,
    unsigned* __restrict__ hT,          // [2 dir][2 parity][32][384] tagged dwords
    _Float16* __restrict__ out16) {     // [32][512][768]
  const int wg = blockIdx.x;
  const int dir = wg / NWG_DIR;
  const int wgj = wg % NWG_DIR;
  const int j0w = wgj * JSPAN;
  const int tid = threadIdx.x, lane = tid & 63, w = tid >> 6;
  const int bt = w & 1, jt = w >> 1;     // btile 0..1, jtile 0..3
  const int c = lane & 15, q = lane >> 4;

  __shared__ __align__(16) _Float16 hS[2][32 * 392];  // h staged, parity dbuf

  // ---- weight B-fragments: [gate][kt], resident all 512 steps ----
  half8_t bfr[3][12];
  {
    const int jglob = j0w + jt * 16 + c;
#pragma unroll
    for (int g = 0; g < 3; ++g) {
      const _Float16* wp = Whh + ((size_t)dir * H3_ + g * H_ + jglob) * H_ + q * 8;
#pragma unroll
      for (int kt = 0; kt < 12; ++kt) bfr[g][kt] = *(const half8_t*)(wp + kt * 32);
    }
  }
  const float* bhh = dir ? bhh_b : bhh_f;
  const int jl = j0w + jt * 16 + c;    // lane's j column
  const int bl0 = bt * 16 + q * 4;     // lane's first b row (covers bl0..bl0+3)
  const float br = bhh[jl], bz = bhh[H_ + jl], bn = bhh[2 * H_ + jl];
  float hc[4] = {0.f, 0.f, 0.f, 0.f};

  unsigned* const hTd = hT + (size_t)dir * 2 * B_ * H_;

  for (int step = 0; step < S_; ++step) {
    const int t = dir ? (S_ - 1 - step) : step;
    const int par = step & 1;

    // xw prefetch (plain cached loads; in flight during the poll)
    const _Float16* xbase = xw + (((size_t)dir * S_ + t) * B_ + bl0) * H3_ + jl;
    _Float16 xr[4], xz[4], xn[4];
#pragma unroll
    for (int r = 0; r < 4; ++r) {
      xr[r] = xbase[(size_t)r * H3_];
      xz[r] = xbase[(size_t)r * H3_ + H_];
      xn[r] = xbase[(size_t)r * H3_ + 2 * H_];
    }

    _Float16* hcur = &hS[par][0];
    if (step == 0) {
      // h0 = 0
      for (int i = tid; i < 32 * 392 / 2; i += 512) ((int*)hcur)[i] = 0;
    } else {
      // gather-as-poll: 6 tagged dwordx4 chunks per thread, spin until all
      // 24 tags == step (data+validity in one round trip).
      const unsigned long long a =
          (unsigned long long)(hTd + (size_t)par * (B_ * H_)) + (size_t)tid * 16;
      const unsigned tg = (unsigned)step;
      int4 v0, v1, v2, v3, v4, v5;
      for (;;) {
        load16_cc6(a, a + 8192, a + 16384, a + 24576, a + 32768, a + 40960,
                   v0, v1, v2, v3, v4, v5);
#define TAGCHK(v) ((((unsigned)(v).x >> 16) ^ tg) | (((unsigned)(v).y >> 16) ^ tg) | \
                   (((unsigned)(v).z >> 16) ^ tg) | (((unsigned)(v).w >> 16) ^ tg))
        unsigned bad = TAGCHK(v0) | TAGCHK(v1) | TAGCHK(v2) |
                       TAGCHK(v3) | TAGCHK(v4) | TAGCHK(v5);
#undef TAGCHK
        if (bad == 0) break;
      }
      // scatter de-tagged halves to LDS: chunk g -> b=g/96, j0=(g%96)*4
      {
        const int4 vv[6] = {v0, v1, v2, v3, v4, v5};
#pragma unroll
        for (int k = 0; k < 6; ++k) {
          int g = tid + (k << 9);
          int b = g / 96;
          int cj = g - b * 96;
          int2 wds;
          wds.x = (vv[k].x & 0xffff) | ((unsigned)vv[k].y << 16);
          wds.y = (vv[k].z & 0xffff) | ((unsigned)vv[k].w << 16);
          *(int2*)&hcur[b * 392 + cj * 4] = wds;
        }
      }
    }
    __syncthreads();

    // MFMA: 3 gate-chains per wave, A-frags from LDS
    floatx4 a0 = {}, a1 = {}, a2 = {};
    {
      const _Float16* hrow = &hcur[(bt * 16 + c) * 392 + q * 8];
#pragma unroll
      for (int kt = 0; kt < 12; ++kt) {
        half8_t af = *(const half8_t*)(hrow + kt * 32);
        a0 = __builtin_amdgcn_mfma_f32_16x16x32_f16(af, bfr[0][kt], a0, 0, 0, 0);
        a1 = __builtin_amdgcn_mfma_f32_16x16x32_f16(af, bfr[1][kt], a1, 0, 0, 0);
        a2 = __builtin_amdgcn_mfma_f32_16x16x32_f16(af, bfr[2][kt], a2, 0, 0, 0);
      }
    }

    // gates in MFMA C-layout: lane r-th acc element = (b = bl0+r, j = jl)
    const unsigned tagw = (unsigned)(step + 1) << 16;
    unsigned* hdst = hTd + ((size_t)((step + 1) & 1) * B_ + bl0) * H_ + jl;
#pragma unroll
    for (int r = 0; r < 4; ++r) {
      float rr = 1.f / (1.f + __expf(-((float)xr[r] + a0[r] + br)));
      float zz = 1.f / (1.f + __expf(-((float)xz[r] + a1[r] + bz)));
      float u = (float)xn[r] + rr * (a2[r] + bn);
      float e = __expf(-2.f * u);
      float nv = (1.f - e) / (1.f + e);
      hc[r] = (1.f - zz) * nv + zz * hc[r];
      _Float16 hh = (_Float16)hc[r];
      unsigned d = tagw | (unsigned)__builtin_bit_cast(unsigned short, hh);
      store4_cc((unsigned long long)(hdst + (size_t)r * H_), d);
      // out16 off the critical path (consumed after kernel boundary)
      out16[((size_t)(bl0 + r) * S_ + t) * TWOH_ + dir * H_ + jl] = hh;
    }
  }
}

// ---------------- attention scores: tanh(out@Wattn^T + b) @ ctx ----------------
__global__ __launch_bounds__(256) void attn_score_kernel(
    const _Float16* __restrict__ A /*out16 [16384][768]*/,
    const _Float16* __restrict__ Bm /*Wattn16 [768][768]*/,
    const float* __restrict__ b_attn, const float* __restrict__ ctx,
    float* __restrict__ scores) {
  __shared__ _Float16 As[64][40];
  __shared__ _Float16 Bs[64][40];
  const int m0 = blockIdx.x * 64, n0 = blockIdx.y * 64;
  const int tid = threadIdx.x, lane = tid & 63, w = tid >> 6;
  const int wm = w >> 1, wn = w & 1;
  const int q = lane >> 4, c = lane & 15;
  floatx4 acc[2][2] = {};

  const int t = tid & 127;
  const int srow = t >> 1, skh = (t & 1) * 16;
  const _Float16* gsrc =
      (tid < 128 ? A + (size_t)(m0 + srow) * D_ : Bm + (size_t)(n0 + srow) * D_) + skh;
  _Float16* ldst = (tid < 128) ? &As[srow][skh] : &Bs[srow][skh];

  for (int k0 = 0; k0 < D_; k0 += 32) {
    half8_t v0 = *(const half8_t*)(gsrc + k0);
    half8_t v1 = *(const half8_t*)(gsrc + k0 + 8);
    __syncthreads();
    *(half8_t*)ldst = v0;
    *(half8_t*)(ldst + 8) = v1;
    __syncthreads();
    half8_t a0 = *(const half8_t*)&As[wm * 32 + c][q * 8];
    half8_t a1 = *(const half8_t*)&As[wm * 32 + 16 + c][q * 8];
    half8_t b0 = *(const half8_t*)&Bs[wn * 32 + c][q * 8];
    half8_t b1 = *(const half8_t*)&Bs[wn * 32 + 16 + c][q * 8];
    acc[0][0] = __builtin_amdgcn_mfma_f32_16x16x32_f16(a0, b0, acc[0][0], 0, 0, 0);
    acc[0][1] = __builtin_amdgcn_mfma_f32_16x16x32_f16(a0, b1, acc[0][1], 0, 0, 0);
    acc[1][0] = __builtin_amdgcn_mfma_f32_16x16x32_f16(a1, b0, acc[1][0], 0, 0, 0);
    acc[1][1] = __builtin_amdgcn_mfma_f32_16x16x32_f16(a1, b1, acc[1][1], 0, 0, 0);
  }
  for (int mi = 0; mi < 2; ++mi)
    for (int ni = 0; ni < 2; ++ni)
      for (int r = 0; r < 4; ++r) {
        int n = n0 + wn * 32 + ni * 16 + c;
        float vv = tanhf(acc[mi][ni][r] + b_attn[n]) * ctx[n];
        vv += __shfl_xor(vv, 1);
        vv += __shfl_xor(vv, 2);
        vv += __shfl_xor(vv, 4);
        vv += __shfl_xor(vv, 8);
        if (c == 0) {
          int m = m0 + wm * 32 + mi * 16 + q * 4 + r;
          atomicAdd(&scores[m], vv);
        }
      }
}

// ---------------- softmax over S per batch ----------------
__global__ __launch_bounds__(256) void softmax_kernel(const float* __restrict__ scores,
                                                      float* __restrict__ attn) {
  const int b = blockIdx.x, tid = threadIdx.x;
  __shared__ float red[8];
  float s0 = scores[b * S_ + tid], s1 = scores[b * S_ + 256 + tid];
  float m = fmaxf(s0, s1);
  for (int off = 1; off < 64; off <<= 1) m = fmaxf(m, __shfl_xor(m, off));
  int wv = tid >> 6;
  if ((tid & 63) == 0) red[wv] = m;
  __syncthreads();
  m = fmaxf(fmaxf(red[0], red[1]), fmaxf(red[2], red[3]));
  float e0 = expf(s0 - m), e1 = expf(s1 - m);
  float sum = e0 + e1;
  for (int off = 1; off < 64; off <<= 1) sum += __shfl_xor(sum, off);
  if ((tid & 63) == 0) red[4 + wv] = sum;
  __syncthreads();
  sum = red[4] + red[5] + red[6] + red[7];
  float inv = 1.0f / sum;
  attn[b * S_ + tid] = e0 * inv;
  attn[b * S_ + 256 + tid] = e1 * inv;
}

// ---------------- doc embedding: attn-weighted sum ----------------
__global__ __launch_bounds__(384) void doc_kernel(const float* __restrict__ attn,
                                                  const _Float16* __restrict__ out16,
                                                  float* __restrict__ dout) {
  const int b = blockIdx.x, tid = threadIdx.x;
  __shared__ float at[S_];
  for (int i = tid; i < S_; i += 384) at[i] = attn[b * S_ + i];
  __syncthreads();
  const half2_t* p = (const half2_t*)(out16 + (size_t)b * S_ * TWOH_) + tid;
  float acc0 = 0.f, acc1 = 0.f;
  for (int s = 0; s < S_; ++s) {
    half2_t h = p[(size_t)s * (TWOH_ / 2)];
    float wgt = at[s];
    acc0 += wgt * (float)h.x;
    acc1 += wgt * (float)h.y;
  }
  dout[b * TWOH_ + tid * 2] = acc0;
  dout[b * TWOH_ + tid * 2 + 1] = acc1;
}

// ---------------- host ----------------
extern "C" void kernel_launch(void* const* d_in, const int* in_sizes, int n_in,
                              void* d_out, int out_size, void* d_ws, size_t ws_size,
                              hipStream_t stream) {
  const float* ip     = (const float*)d_in[0];
  const float* W_ih_f = (const float*)d_in[1];
  const float* W_hh_f = (const float*)d_in[2];
  const float* b_ih_f = (const float*)d_in[3];
  const float* b_hh_f_p = (const float*)d_in[4];
  const float* W_ih_b = (const float*)d_in[5];
  const float* W_hh_b = (const float*)d_in[6];
  const float* b_ih_b = (const float*)d_in[7];
  const float* b_hh_b_p = (const float*)d_in[8];
  const float* W_attn = (const float*)d_in[9];
  const float* b_attn = (const float*)d_in[10];
  const float* context = (const float*)d_in[11];
  float* doc = (float*)d_out;

  char* ws = (char*)d_ws;
  size_t off = 0;
  auto alloc = [&](size_t bytes) {
    char* p = ws + off;
    off += (bytes + 255) & ~(size_t)255;
    return p;
  };
  _Float16* ip16    = (_Float16*)alloc((size_t)M_ * D_ * 2);          // 25.2 MB
  _Float16* Wih16   = (_Float16*)alloc((size_t)N2_ * D_ * 2);         // 3.5 MB
  _Float16* Whh16   = (_Float16*)alloc((size_t)2 * H3_ * H_ * 2);     // 1.8 MB
  _Float16* Wattn16 = (_Float16*)alloc((size_t)TWOH_ * TWOH_ * 2);    // 1.2 MB
  _Float16* xw      = (_Float16*)alloc((size_t)2 * S_ * B_ * H3_ * 2);// 75.5 MB
  _Float16* out16   = (_Float16*)alloc((size_t)B_ * S_ * TWOH_ * 2);  // 25.2 MB
  unsigned* hT      = (unsigned*)alloc((size_t)2 * 2 * B_ * H_ * 4);  // 192 KB tagged
  float* scores     = (float*)alloc((size_t)M_ * 4);
  float* attn       = (float*)alloc((size_t)M_ * 4);

  // 1. converts
  cvt_f32_f16_kernel<<<(M_ * D_ / 4 + 255) / 256, 256, 0, stream>>>(ip, ip16, M_ * D_ / 4);
  cvt_f32_f16_kernel<<<(H3_ * D_ / 4 + 255) / 256, 256, 0, stream>>>(W_ih_f, Wih16, H3_ * D_ / 4);
  cvt_f32_f16_kernel<<<(H3_ * D_ / 4 + 255) / 256, 256, 0, stream>>>(W_ih_b, Wih16 + (size_t)H3_ * D_, H3_ * D_ / 4);
  cvt_f32_f16_kernel<<<(H3_ * H_ / 4 + 255) / 256, 256, 0, stream>>>(W_hh_f, Whh16, H3_ * H_ / 4);
  cvt_f32_f16_kernel<<<(H3_ * H_ / 4 + 255) / 256, 256, 0, stream>>>(W_hh_b, Whh16 + (size_t)H3_ * H_, H3_ * H_ / 4);
  cvt_f32_f16_kernel<<<(TWOH_ * TWOH_ / 4 + 255) / 256, 256, 0, stream>>>(W_attn, Wattn16, TWOH_ * TWOH_ / 4);

  // 2. input projection GEMM
  gemm_xw_kernel<<<dim3(M_ / 64, N2_ / 64), 256, 0, stream>>>(ip16, Wih16, b_ih_f, b_ih_b, xw);

  // 3. recurrence: zero tagged h buffer (tag 0 != any expected tag 1..512)
  hipMemsetAsync(hT, 0, (size_t)2 * 2 * B_ * H_ * 4, stream);
  {
    const _Float16* xw_a = xw;
    const _Float16* whh_a = Whh16;
    const float* bf_a = b_hh_f_p;
    const float* bb_a = b_hh_b_p;
    unsigned* ht_a = hT;
    _Float16* o16_a = out16;
    void* args[] = {(void*)&xw_a, (void*)&whh_a, (void*)&bf_a, (void*)&bb_a,
                    (void*)&ht_a, (void*)&o16_a};
    hipLaunchCooperativeKernel((const void*)gru_mfma_kernel, dim3(2 * NWG_DIR),
                               dim3(512), args, 0, stream);
  }

  // 4. attention scores
  hipMemsetAsync(scores, 0, (size_t)M_ * 4, stream);
  attn_score_kernel<<<dim3(M_ / 64, TWOH_ / 64), 256, 0, stream>>>(out16, Wattn16, b_attn, context, scores);

  // 5. softmax + weighted sum
  softmax_kernel<<<B_, 256, 0, stream>>>(scores, attn);
  doc_kernel<<<B_, 384, 0, stream>>>(attn, out16, doc);
}